// Round 12
// baseline (204.877 us; speedup 1.0000x reference)
//
#include <hip/hip_runtime.h>
#include <hip/hip_bf16.h>

typedef __bf16 bf16x8 __attribute__((ext_vector_type(8)));
typedef __bf16 bf16x4 __attribute__((ext_vector_type(4)));
typedef float f32x4 __attribute__((ext_vector_type(4)));

#define MFMA(a, b, c) __builtin_amdgcn_mfma_f32_16x16x32_bf16(a, b, c, 0, 0, 0)

// ws layout (bf16 elem offsets) — weights in MFMA B-fragment order:
// frag[(nt*nKT + kt)*64 + lane][j] = W[kt*32 + (lane>>4)*8 + j][nt*16 + (lane&15)]
constexpr int MP_OFF = 0;
constexpr int W1_OFF = 8192;
constexpr int W2_OFF = 49152;
constexpr int W3_OFF = 114688;
constexpr int W4_OFF = 155648;
constexpr int WS_TOTAL = 221184;
constexpr size_t WS_BYTES = (size_t)WS_TOTAL * 2;

__device__ __forceinline__ float ldf(const void* p, int i, bool f32) {
    return f32 ? ((const float*)p)[i] : (float)(((const __bf16*)p)[i]);
}
__device__ __forceinline__ int geti(const int* p, int i, bool i64) {
    return p[i64 ? 2 * i : i];
}

// swz v3: thread <-> destination fragment row (8 elems). One coalesced 16B
// store; 8 reads land in 32B segments (4 segs/wave/load). Dtype detect folded
// in per block (fp32-misread-as-bf16 shows exponent-0xFF halfwords).
__global__ void swz(const void* __restrict__ mp, const void* __restrict__ w1,
                    const void* __restrict__ w2, const void* __restrict__ w3,
                    const void* __restrict__ w4, __bf16* __restrict__ ws) {
    __shared__ int sflag;
    if (threadIdx.x == 0) sflag = 0;
    __syncthreads();
    {
        const unsigned short* uw = (const unsigned short*)w2;
        int bad = 0;
        for (int i = threadIdx.x; i < 8192; i += 256)
            if (((uw[i] >> 7) & 0xFF) == 0xFF) bad = 1;
        if (bad) atomicOr(&sflag, 1);
    }
    __syncthreads();
    bool f32 = sflag != 0;

    int r = blockIdx.x * 256 + threadIdx.x;  // global frag row, 27648 total
    if (r >= 27648) return;
    const void* src;
    int lr, nKT, nsh, style, K;
    if (r < 1024)       { src = mp; lr = r;         nKT = 2; nsh = 7; style = 0; K = 46; }
    else if (r < 6144)  { src = w1; lr = r - 1024;  nKT = 5; nsh = 8; style = 1; K = 157; }
    else if (r < 14336) { src = w2; lr = r - 6144;  nKT = 8; nsh = 8; style = 0; K = 256; }
    else if (r < 19456) { src = w3; lr = r - 14336; nKT = 5; nsh = 8; style = 1; K = 157; }
    else                { src = w4; lr = r - 19456; nKT = 8; nsh = 8; style = 0; K = 256; }
    int t = lr >> 6, lanep = lr & 63;
    int nt = t / nKT, kt = t % nKT;
    int kq = lanep >> 4, nlo = lanep & 15;
    int n = nt * 16 + nlo;
    int N = 1 << nsh;
    bf16x8 v;
#pragma unroll
    for (int j = 0; j < 8; ++j) {
        int kp = kt * 32 + kq * 8 + j;
        int ks = kp;
        bool ok = true;
        if (style == 1) { if (kp >= 32) ks = kp - 3; else if (kp >= 29) ok = false; }
        if (ks >= K) ok = false;
        v[j] = ok ? (__bf16)ldf(src, ks * N + n, f32) : (__bf16)0.f;
    }
    *(bf16x8*)(ws + r * 8) = v;
}

// Direct B-fragment gather fallback (ws too small). Same lane mapping as A-frag.
__device__ __forceinline__ bf16x8 gatherB(const void* W, bool f32, int style,
                                          int K, int N, int k0, int n, int q) {
    bf16x8 r;
#pragma unroll
    for (int j = 0; j < 8; ++j) {
        int k = k0 + q * 8 + j;
        bool ok = true;
        if (style == 1) { if (k >= 32) k -= 3; else if (k >= 29) ok = false; }
        if (k >= K) ok = false;
        float v = ok ? ldf(W, k * N + n, f32) : 0.f;
        r[j] = (__bf16)v;
    }
    return r;
}

// LDS (46,064 B -> 3 blocks/CU at any plausible granularity):
//   s_union[0..8192)    : edge-A frags (chunks of <=8 mt) / h frags (<=2 mt), aliased
//   s_union[8192..10112): rowbuf 16 x 120 (dead after last buildA; s_q aliases head)
//   s_inp[12800]        : inp frags, 5 mt x 5 kt x 512
template <int PC, int PBASE>
__device__ __forceinline__ void buildA(__bf16* sA, const __bf16* rb, const int* s_esrc,
                                       const int* s_pid0, const int* s_pid1, int tid) {
    for (int i = tid; i < 16 * PC * 8; i += 512) {
        int r = i >> 3, oct = i & 7;
        int lb = r / PC, p = PBASE + r % PC;
        const __bf16* row = rb + lb * 120;
        bf16x8 v;
#pragma unroll
        for (int j = 0; j < 8; ++j) {
            int k = oct * 8 + j;
            __bf16 x = (__bf16)0.f;
            if (k < 10) x = row[k];
            else if (k < 14) x = row[85 + (k - 10)];
            else if (k < 16) x = row[89 + ((k == 14) ? s_pid0[p] : s_pid1[p])];
            else if (k < 31) x = row[10 + s_esrc[p] * 15 + (k - 16)];
            else if (k < 46) x = row[10 + (p >> 2) * 15 + (k - 31)];
            v[j] = x;
        }
        int t = (r >> 4) * 2 + (oct >> 2);
        int lanep = ((oct & 3) << 4) | (r & 15);
        *(bf16x8*)(sA + t * 512 + lanep * 8) = v;
    }
}

// stage1: A=edges, B=mp_w frags; 8 waves x 1 nt. Quad holds one (b,o) group.
template <int PC, int PBASE, bool DW>
__device__ __forceinline__ void stage1(const __bf16* Wf, const void* Wn, bool fW,
                                       const void* mp_b, const __bf16* sA,
                                       __bf16* s_inp, int wave, int lane) {
    int q = lane >> 4, c = lane & 15;
    int nt = wave;
    float mb = ldf(mp_b, nt * 16 + c, fW);
    bf16x8 bw[2];
#pragma unroll
    for (int kt = 0; kt < 2; ++kt) {
        if constexpr (DW) bw[kt] = gatherB(Wn, fW, 0, 46, 128, kt * 32, nt * 16 + c, q);
        else bw[kt] = *(const bf16x8*)(Wf + (nt * 2 + kt) * 512 + lane * 8);
    }
    f32x4 zero4 = {0.f, 0.f, 0.f, 0.f};
#pragma unroll
    for (int mtg = 0; mtg < PC / 4; ++mtg) {
        f32x4 acc[4];
#pragma unroll
        for (int m = 0; m < 4; ++m) acc[m] = zero4;
#pragma unroll
        for (int kt = 0; kt < 2; ++kt)
#pragma unroll
            for (int m = 0; m < 4; ++m) {
                bf16x8 a = *(const bf16x8*)(sA + ((mtg * 4 + m) * 2 + kt) * 512 + lane * 8);
                acc[m] = MFMA(a, bw[kt], acc[m]);
            }
#pragma unroll
        for (int m = 0; m < 4; ++m) {
            int mt = mtg * 4 + m;
            float sum = 0.f;
#pragma unroll
            for (int rr = 0; rr < 4; ++rr) {
                float z = acc[m][rr] + mb;
                sum += (z > 0.f) ? z : 0.f;
            }
            int r0 = mt * 16 + q * 4;
            int lb = r0 / PC;
            int o = (PBASE + (r0 % PC)) >> 2;
            int rinp = lb * 5 + o;
            int kk = 32 + nt * 16 + c;
            s_inp[((rinp >> 4) * 5 + (kk >> 5)) * 512 +
                  ((((kk & 31) >> 3) << 4) + (rinp & 15)) * 8 + (kk & 7)] = (__bf16)sum;
        }
    }
}

// stage2 SWAPPED: D'[hcol][row] = MFMA(A=W1-frag, B=inp-frag); 8 waves x 2 ht.
// Epilogue: relu(+bias) -> one ds_write_b64 lands in exact A-frag layout for stage3.
template <int MTN, bool DW>
__device__ __forceinline__ void stage2s(int mbase, const __bf16* Wf, const void* Wn,
                                        bool fW, const void* Ba, __bf16* s_h,
                                        const __bf16* s_inp, int wave, int lane) {
    int q = lane >> 4, c = lane & 15;
    f32x4 zero4 = {0.f, 0.f, 0.f, 0.f};
    float bias_r[2][4];
#pragma unroll
    for (int n = 0; n < 2; ++n)
#pragma unroll
        for (int rg = 0; rg < 4; ++rg)
            bias_r[n][rg] = ldf(Ba, (wave * 2 + n) * 16 + q * 4 + rg, fW);
#pragma unroll
    for (int n = 0; n < 2; ++n) {
        int ht = wave * 2 + n;
        bf16x8 aw[5];
#pragma unroll
        for (int kt = 0; kt < 5; ++kt) {
            if constexpr (DW) aw[kt] = gatherB(Wn, fW, 1, 157, 256, kt * 32, ht * 16 + c, q);
            else aw[kt] = *(const bf16x8*)(Wf + (ht * 5 + kt) * 512 + lane * 8);
        }
        f32x4 acc[MTN];
#pragma unroll
        for (int m = 0; m < MTN; ++m) acc[m] = zero4;
#pragma unroll
        for (int kt = 0; kt < 5; ++kt) {
#pragma unroll
            for (int m = 0; m < MTN; ++m) {
                bf16x8 b = *(const bf16x8*)(s_inp + ((mbase + m) * 5 + kt) * 512 + lane * 8);
                acc[m] = MFMA(aw[kt], b, acc[m]);
            }
        }
#pragma unroll
        for (int m = 0; m < MTN; ++m) {
            bf16x4 hv;
#pragma unroll
            for (int rg = 0; rg < 4; ++rg) {
                float z = acc[m][rg] + bias_r[n][rg];
                hv[rg] = (__bf16)((z > 0.f) ? z : 0.f);
            }
            *(bf16x4*)(s_h + (m * 8 + (ht >> 1)) * 512 +
                       ((((ht & 1) * 2 + (q >> 1)) << 4) | c) * 8 + ((q & 1) << 2)) = hv;
        }
    }
}

// stage3 SWAPPED: D'[ncol][row] = MFMA(A=W2-frag, B=h-frag); 8 waves x 2 nt.
template <int MTN, bool DW>
__device__ __forceinline__ void stage3s(int mbase, const __bf16* Wf, const void* Wn,
                                        bool fW, const void* Bb, const void* Rh,
                                        const __bf16* s_h, float* s_qp, int wave, int lane) {
    int q = lane >> 4, c = lane & 15;
    f32x4 zero4 = {0.f, 0.f, 0.f, 0.f};
    float bias_r[2][4], rho_r[2][4];
#pragma unroll
    for (int n = 0; n < 2; ++n)
#pragma unroll
        for (int rg = 0; rg < 4; ++rg) {
            int ncol = (wave * 2 + n) * 16 + q * 4 + rg;
            bias_r[n][rg] = ldf(Bb, ncol, fW);
            rho_r[n][rg] = ldf(Rh, ncol, fW);
        }
    float rowsum[MTN];
#pragma unroll
    for (int m = 0; m < MTN; ++m) rowsum[m] = 0.f;
#pragma unroll
    for (int n = 0; n < 2; ++n) {
        int nt = wave * 2 + n;
        bf16x8 aw[8];
#pragma unroll
        for (int kt = 0; kt < 8; ++kt) {
            if constexpr (DW) aw[kt] = gatherB(Wn, fW, 0, 256, 256, kt * 32, nt * 16 + c, q);
            else aw[kt] = *(const bf16x8*)(Wf + (nt * 8 + kt) * 512 + lane * 8);
        }
        f32x4 acc[MTN];
#pragma unroll
        for (int m = 0; m < MTN; ++m) acc[m] = zero4;
#pragma unroll
        for (int kt = 0; kt < 8; ++kt) {
#pragma unroll
            for (int m = 0; m < MTN; ++m) {
                bf16x8 b = *(const bf16x8*)(s_h + (m * 8 + kt) * 512 + lane * 8);
                acc[m] = MFMA(aw[kt], b, acc[m]);
            }
        }
#pragma unroll
        for (int m = 0; m < MTN; ++m)
#pragma unroll
            for (int rg = 0; rg < 4; ++rg) {
                float z = acc[m][rg] + bias_r[n][rg];
                z = (z > 0.f) ? z : 0.f;
                rowsum[m] += z * rho_r[n][rg];
            }
    }
#pragma unroll
    for (int m = 0; m < MTN; ++m) {
        float v = rowsum[m];
        v += __shfl_xor(v, 16);
        v += __shfl_xor(v, 32);
        if (q == 0) {
            int r0 = (mbase + m) * 16 + c;  // rinp = b*5+o
            atomicAdd(&s_qp[r0 / 5], v);
        }
    }
}

template <bool DW>
__global__ __launch_bounds__(512, 4) void gn_main(
    const void* __restrict__ obs, const void* __restrict__ act,
    const void* __restrict__ ag, const void* __restrict__ g,
    const void* __restrict__ mp_b, const void* __restrict__ b1,
    const void* __restrict__ b2, const void* __restrict__ b3,
    const void* __restrict__ b4, const void* __restrict__ rw1,
    const void* __restrict__ rb1, const void* __restrict__ rw2,
    const void* __restrict__ rb2, const int* __restrict__ eA,
    const int* __restrict__ eB, const int* __restrict__ pred_ids,
    const int* __restrict__ incoming, const __bf16* __restrict__ wsW,
    const void* __restrict__ mp_w, const void* __restrict__ w1,
    const void* __restrict__ w2, const void* __restrict__ w3,
    const void* __restrict__ w4, float* __restrict__ out, int Btot) {
    __shared__ __align__(16) __bf16 s_union[10112];
    __shared__ __align__(16) __bf16 s_inp[12800];
    __shared__ int s_esrc[20], s_pid0[20], s_pid1[20];

    int tid = threadIdx.x, lane = tid & 63, wave = tid >> 6;
    __bf16* rb = s_union + 8192;
    float* s_q = (float*)(s_union + 8192);  // aliases rowbuf head (dead by stage3)
    int b0 = blockIdx.x * 16;

    // ---- dtype flags (per-wave ballot scan; uniform per wave) ----
    bool fI, fW;
    {
        const unsigned short* uo = (const unsigned short*)obs;
        const unsigned short* uw = (const unsigned short*)w2;
        int d0 = 0, d1 = 0;
        for (int i = lane; i < 8192; i += 64) {
            if (((uo[i] >> 7) & 0xFF) == 0xFF) d0 = 1;
            if (((uw[i] >> 7) & 0xFF) == 0xFF) d1 = 1;
        }
        fI = __ballot(d0) != 0;
        fW = __ballot(d1) != 0;
    }

    // ---- int width + src/dst disambiguation ----
    bool i64_i = (incoming[1] == 0);
    bool i64_p = (pred_ids[1] == 0);
    bool i64_e = (eA[9] == 0);
    const int* es = (geti(eA, 4, i64_e) == 1) ? eA : eB;

    if (tid < 20) {
        int e = geti(incoming, tid, i64_i);  // tid = o*4+j; edge p=tid has dst o=tid/4
        s_esrc[tid] = geti(es, e, i64_e);
        s_pid0[tid] = geti(pred_ids, 2 * e, i64_p);
        s_pid1[tid] = geti(pred_ids, 2 * e + 1, i64_p);
    }

    for (int i = tid; i < 16 * 120; i += 512) {
        int lb = i / 120, cidx = i % 120;
        int bg = b0 + lb;
        float v = 0.f;
        if (cidx < 85) v = ldf(obs, bg * 85 + cidx, fI);
        else if (cidx < 89) v = ldf(act, bg * 4 + (cidx - 85), fI);
        else if (cidx < 119) {
            int t = cidx - 89;
            v = ldf(g, bg * 30 + t, fI) - ldf(ag, bg * 30 + t, fI);
        }
        rb[i] = (__bf16)v;
    }
    __syncthreads();

    // inp kt=0 plane (k<32) as b128 blocks
    for (int i = tid; i < 80 * 4; i += 512) {
        int r = i >> 2, oct = i & 3;
        int lb = r / 5, o = r % 5;
        const __bf16* row = rb + lb * 120;
        bf16x8 v;
#pragma unroll
        for (int j = 0; j < 8; ++j) {
            int k = oct * 8 + j;
            __bf16 x = (__bf16)0.f;
            if (k < 4) x = row[85 + k];
            else if (k < 14) x = row[k - 4];
            else if (k < 29) x = row[10 + o * 15 + (k - 14)];
            v[j] = x;
        }
        *(bf16x8*)(s_inp + (r >> 4) * 2560 + ((oct << 4) | (r & 15)) * 8) = v;
    }
    buildA<8, 0>(s_union, rb, s_esrc, s_pid0, s_pid1, tid);
    __syncthreads();
    stage1<8, 0, DW>(wsW + MP_OFF, mp_w, fW, mp_b, s_union, s_inp, wave, lane);
    __syncthreads();
    buildA<8, 8>(s_union, rb, s_esrc, s_pid0, s_pid1, tid);
    __syncthreads();
    stage1<8, 8, DW>(wsW + MP_OFF, mp_w, fW, mp_b, s_union, s_inp, wave, lane);
    __syncthreads();
    buildA<4, 16>(s_union, rb, s_esrc, s_pid0, s_pid1, tid);
    __syncthreads();
    if (tid < 32) s_q[tid] = 0.f;  // rowbuf dead from here on
    stage1<4, 16, DW>(wsW + MP_OFF, mp_w, fW, mp_b, s_union, s_inp, wave, lane);
    __syncthreads();

    for (int P = 0; P < 2; ++P) {
        const __bf16* Wa = wsW + (P ? W3_OFF : W1_OFF);
        const __bf16* Wb = wsW + (P ? W4_OFF : W2_OFF);
        const void* Wan = P ? w3 : w1;
        const void* Wbn = P ? w4 : w2;
        const void* ba = P ? b3 : b1;
        const void* bb = P ? b4 : b2;
        const void* rho = P ? rw2 : rw1;
        float* qp = s_q + P * 16;
        stage2s<2, DW>(0, Wa, Wan, fW, ba, s_union, s_inp, wave, lane);
        __syncthreads();
        stage3s<2, DW>(0, Wb, Wbn, fW, bb, rho, s_union, qp, wave, lane);
        __syncthreads();
        stage2s<2, DW>(2, Wa, Wan, fW, ba, s_union, s_inp, wave, lane);
        __syncthreads();
        stage3s<2, DW>(2, Wb, Wbn, fW, bb, rho, s_union, qp, wave, lane);
        __syncthreads();
        stage2s<1, DW>(4, Wa, Wan, fW, ba, s_union, s_inp, wave, lane);
        __syncthreads();
        stage3s<1, DW>(4, Wb, Wbn, fW, bb, rho, s_union, qp, wave, lane);
        __syncthreads();
    }

    if (tid < 16) {
        out[b0 + tid] = s_q[tid] + ldf(rb1, 0, fW);
        out[Btot + b0 + tid] = s_q[16 + tid] + ldf(rb2, 0, fW);
    }
}

extern "C" void kernel_launch(void* const* d_in, const int* in_sizes, int n_in,
                              void* d_out, int out_size, void* d_ws, size_t ws_size,
                              hipStream_t stream) {
    int B = out_size / 2;  // 16384

    const void *obs = nullptr, *act = nullptr, *ag = nullptr, *g = nullptr;
    const void *mp_w = nullptr, *mp_b = nullptr;
    const void *w1 = nullptr, *b1 = nullptr, *w2 = nullptr, *b2 = nullptr;
    const void *w3 = nullptr, *b3 = nullptr, *w4 = nullptr, *b4 = nullptr;
    const void *rw1 = nullptr, *rb1 = nullptr, *rw2 = nullptr, *rb2 = nullptr;
    const int *eA = nullptr, *eB = nullptr, *pred = nullptr, *inc = nullptr;
    int c30 = 0, c256 = 0, c1 = 0, c40k = 0, c65k = 0, c20 = 0;
    for (int i = 0; i < n_in; ++i) {
        int sz = in_sizes[i];
        const void* p = d_in[i];
        if (sz == B * 85) obs = p;
        else if (sz == B * 30) { if (c30++ == 0) ag = p; else g = p; }
        else if (sz == 5888) mp_w = p;
        else if (sz == 128) mp_b = p;
        else if (sz == 40192) { if (c40k++ == 0) w1 = p; else w3 = p; }
        else if (sz == 65536 || sz == B * 4) {
            int c = c65k++;
            if (c == 0) act = p; else if (c == 1) w2 = p; else w4 = p;
        }
        else if (sz == 256) {
            int c = c256++;
            if (c == 0) b1 = p; else if (c == 1) b2 = p; else if (c == 2) b3 = p;
            else if (c == 3) b4 = p; else if (c == 4) rw1 = p; else rw2 = p;
        }
        else if (sz == 1) { if (c1++ == 0) rb1 = p; else rb2 = p; }
        else if (sz == 40) pred = (const int*)p;
        else if (sz == 20) {
            int c = c20++;
            if (c == 0) eA = (const int*)p;
            else if (c == 1) eB = (const int*)p;
            else inc = (const int*)p;
        }
    }
    if (!obs || !act || !ag || !g || !mp_w || !mp_b || !w1 || !b1 || !w2 || !b2 ||
        !w3 || !b3 || !w4 || !b4 || !rw1 || !rb1 || !rw2 || !rb2 || !eA || !eB ||
        !pred || !inc) {
        obs = d_in[0]; act = d_in[1]; ag = d_in[2]; g = d_in[3];
        mp_w = d_in[4]; mp_b = d_in[5]; w1 = d_in[6]; b1 = d_in[7];
        w2 = d_in[8]; b2 = d_in[9]; w3 = d_in[10]; b3 = d_in[11];
        w4 = d_in[12]; b4 = d_in[13]; rw1 = d_in[14]; rb1 = d_in[15];
        rw2 = d_in[16]; rb2 = d_in[17];
        eA = (const int*)d_in[18]; eB = (const int*)d_in[19];
        pred = (const int*)d_in[20]; inc = (const int*)d_in[21];
    }

    float* out = (float*)d_out;
    __bf16* wsW = (__bf16*)d_ws;
    bool use_ws = ws_size >= WS_BYTES;
    int grid = B / 16;

    if (use_ws) {
        swz<<<108, 256, 0, stream>>>(mp_w, w1, w2, w3, w4, wsW);
        gn_main<false><<<grid, 512, 0, stream>>>(
            obs, act, ag, g, mp_b, b1, b2, b3, b4, rw1, rb1, rw2, rb2,
            eA, eB, pred, inc, wsW, mp_w, w1, w2, w3, w4, out, B);
    } else {
        gn_main<true><<<grid, 512, 0, stream>>>(
            obs, act, ag, g, mp_b, b1, b2, b3, b4, rw1, rb1, rw2, rb2,
            eA, eB, pred, inc, wsW, mp_w, w1, w2, w3, w4, out, B);
    }
}

// Round 13
// 193.483 us; speedup vs baseline: 1.0589x; 1.0589x over previous
//
#include <hip/hip_runtime.h>
#include <hip/hip_bf16.h>

typedef __bf16 bf16x8 __attribute__((ext_vector_type(8)));
typedef __bf16 bf16x4 __attribute__((ext_vector_type(4)));
typedef float f32x4 __attribute__((ext_vector_type(4)));

#define MFMA(a, b, c) __builtin_amdgcn_mfma_f32_16x16x32_bf16(a, b, c, 0, 0, 0)

// ws layout (bf16 elem offsets) — weights in MFMA B-fragment order:
// frag[(nt*nKT + kt)*64 + lane][j] = W[kt*32 + (lane>>4)*8 + j][nt*16 + (lane&15)]
constexpr int MP_OFF = 0;
constexpr int W1_OFF = 8192;
constexpr int W2_OFF = 49152;
constexpr int W3_OFF = 114688;
constexpr int W4_OFF = 155648;
constexpr int WS_TOTAL = 221184;
constexpr size_t WS_BYTES = (size_t)WS_TOTAL * 2;

__device__ __forceinline__ float ldf(const void* p, int i, bool f32) {
    return f32 ? ((const float*)p)[i] : (float)(((const __bf16*)p)[i]);
}
__device__ __forceinline__ int geti(const int* p, int i, bool i64) {
    return p[i64 ? 2 * i : i];
}

// swz v3: thread <-> destination fragment row (8 elems). One coalesced 16B
// store; 8 reads land in 32B segments. Dtype detect folded in per block
// (fp32-misread-as-bf16 shows exponent-0xFF halfwords).
__global__ void swz(const void* __restrict__ mp, const void* __restrict__ w1,
                    const void* __restrict__ w2, const void* __restrict__ w3,
                    const void* __restrict__ w4, __bf16* __restrict__ ws) {
    __shared__ int sflag;
    if (threadIdx.x == 0) sflag = 0;
    __syncthreads();
    {
        const unsigned short* uw = (const unsigned short*)w2;
        int bad = 0;
        for (int i = threadIdx.x; i < 8192; i += 256)
            if (((uw[i] >> 7) & 0xFF) == 0xFF) bad = 1;
        if (bad) atomicOr(&sflag, 1);
    }
    __syncthreads();
    bool f32 = sflag != 0;

    int r = blockIdx.x * 256 + threadIdx.x;  // global frag row, 27648 total
    if (r >= 27648) return;
    const void* src;
    int lr, nKT, nsh, style, K;
    if (r < 1024)       { src = mp; lr = r;         nKT = 2; nsh = 7; style = 0; K = 46; }
    else if (r < 6144)  { src = w1; lr = r - 1024;  nKT = 5; nsh = 8; style = 1; K = 157; }
    else if (r < 14336) { src = w2; lr = r - 6144;  nKT = 8; nsh = 8; style = 0; K = 256; }
    else if (r < 19456) { src = w3; lr = r - 14336; nKT = 5; nsh = 8; style = 1; K = 157; }
    else                { src = w4; lr = r - 19456; nKT = 8; nsh = 8; style = 0; K = 256; }
    int t = lr >> 6, lanep = lr & 63;
    int nt = t / nKT, kt = t % nKT;
    int kq = lanep >> 4, nlo = lanep & 15;
    int n = nt * 16 + nlo;
    int N = 1 << nsh;
    bf16x8 v;
#pragma unroll
    for (int j = 0; j < 8; ++j) {
        int kp = kt * 32 + kq * 8 + j;
        int ks = kp;
        bool ok = true;
        if (style == 1) { if (kp >= 32) ks = kp - 3; else if (kp >= 29) ok = false; }
        if (ks >= K) ok = false;
        v[j] = ok ? (__bf16)ldf(src, ks * N + n, f32) : (__bf16)0.f;
    }
    *(bf16x8*)(ws + r * 8) = v;
}

// Direct B-fragment gather fallback (ws too small). Same lane mapping as A-frag.
__device__ __forceinline__ bf16x8 gatherB(const void* W, bool f32, int style,
                                          int K, int N, int k0, int n, int q) {
    bf16x8 r;
#pragma unroll
    for (int j = 0; j < 8; ++j) {
        int k = k0 + q * 8 + j;
        bool ok = true;
        if (style == 1) { if (k >= 32) k -= 3; else if (k >= 29) ok = false; }
        if (k >= K) ok = false;
        float v = ok ? ldf(W, k * N + n, f32) : 0.f;
        r[j] = (__bf16)v;
    }
    return r;
}

// LDS (54,256 B -> alloc 54,272; 512-thr blocks, 8 waves):
//   s_union[0..12288)    : edge-A frags (chunks 12/8 mt) / h frags (<=3 mt), aliased
//   s_union[12288..14208): rowbuf 16 x 120 (dead after last buildA; s_q aliases head)
//   s_inp[12800]         : inp frags, 5 mt x 5 kt x 512
template <int PC, int PBASE>
__device__ __forceinline__ void buildA(__bf16* sA, const __bf16* rb, const int* s_esrc,
                                       const int* s_pid0, const int* s_pid1, int tid) {
    for (int i = tid; i < 16 * PC * 8; i += 512) {
        int r = i >> 3, oct = i & 7;
        int lb = r / PC, p = PBASE + r % PC;
        const __bf16* row = rb + lb * 120;
        bf16x8 v;
#pragma unroll
        for (int j = 0; j < 8; ++j) {
            int k = oct * 8 + j;
            __bf16 x = (__bf16)0.f;
            if (k < 10) x = row[k];
            else if (k < 14) x = row[85 + (k - 10)];
            else if (k < 16) x = row[89 + ((k == 14) ? s_pid0[p] : s_pid1[p])];
            else if (k < 31) x = row[10 + s_esrc[p] * 15 + (k - 16)];
            else if (k < 46) x = row[10 + (p >> 2) * 15 + (k - 31)];
            v[j] = x;
        }
        int t = (r >> 4) * 2 + (oct >> 2);
        int lanep = ((oct & 3) << 4) | (r & 15);
        *(bf16x8*)(sA + t * 512 + lanep * 8) = v;
    }
}

// stage1: A=edges, B=mp_w frags; 8 waves x 1 nt; weights hoisted out of mtg loop.
template <int PC, int PBASE, bool DW>
__device__ __forceinline__ void stage1(const __bf16* Wf, const void* Wn, bool fW,
                                       const void* mp_b, const __bf16* sA,
                                       __bf16* s_inp, int wave, int lane) {
    int q = lane >> 4, c = lane & 15;
    int nt = wave;
    float mb = ldf(mp_b, nt * 16 + c, fW);
    bf16x8 bw[2];
#pragma unroll
    for (int kt = 0; kt < 2; ++kt) {
        if constexpr (DW) bw[kt] = gatherB(Wn, fW, 0, 46, 128, kt * 32, nt * 16 + c, q);
        else bw[kt] = *(const bf16x8*)(Wf + (nt * 2 + kt) * 512 + lane * 8);
    }
    f32x4 zero4 = {0.f, 0.f, 0.f, 0.f};
#pragma unroll
    for (int mtg = 0; mtg < PC / 4; ++mtg) {
        f32x4 acc[4];
#pragma unroll
        for (int m = 0; m < 4; ++m) acc[m] = zero4;
#pragma unroll
        for (int kt = 0; kt < 2; ++kt)
#pragma unroll
            for (int m = 0; m < 4; ++m) {
                bf16x8 a = *(const bf16x8*)(sA + ((mtg * 4 + m) * 2 + kt) * 512 + lane * 8);
                acc[m] = MFMA(a, bw[kt], acc[m]);
            }
#pragma unroll
        for (int m = 0; m < 4; ++m) {
            int mt = mtg * 4 + m;
            float sum = 0.f;
#pragma unroll
            for (int rr = 0; rr < 4; ++rr) {
                float z = acc[m][rr] + mb;
                sum += (z > 0.f) ? z : 0.f;
            }
            int r0 = mt * 16 + q * 4;
            int lb = r0 / PC;
            int o = (PBASE + (r0 % PC)) >> 2;
            int rinp = lb * 5 + o;
            int kk = 32 + nt * 16 + c;
            s_inp[((rinp >> 4) * 5 + (kk >> 5)) * 512 +
                  ((((kk & 31) >> 3) << 4) + (rinp & 15)) * 8 + (kk & 7)] = (__bf16)sum;
        }
    }
}

// stage2 SWAPPED: D'[hcol][row] = MFMA(A=W1-frag, B=inp-frag); 8 waves x 2 ht.
// Epilogue: relu(+bias) -> one ds_write_b64 lands in exact A-frag layout for stage3.
template <int MTN, bool DW>
__device__ __forceinline__ void stage2s(int mbase, const __bf16* Wf, const void* Wn,
                                        bool fW, const void* Ba, __bf16* s_h,
                                        const __bf16* s_inp, int wave, int lane) {
    int q = lane >> 4, c = lane & 15;
    f32x4 zero4 = {0.f, 0.f, 0.f, 0.f};
    float bias_r[2][4];
#pragma unroll
    for (int n = 0; n < 2; ++n)
#pragma unroll
        for (int rg = 0; rg < 4; ++rg)
            bias_r[n][rg] = ldf(Ba, (wave * 2 + n) * 16 + q * 4 + rg, fW);
#pragma unroll
    for (int n = 0; n < 2; ++n) {
        int ht = wave * 2 + n;
        bf16x8 aw[5];
#pragma unroll
        for (int kt = 0; kt < 5; ++kt) {
            if constexpr (DW) aw[kt] = gatherB(Wn, fW, 1, 157, 256, kt * 32, ht * 16 + c, q);
            else aw[kt] = *(const bf16x8*)(Wf + (ht * 5 + kt) * 512 + lane * 8);
        }
        f32x4 acc[MTN];
#pragma unroll
        for (int m = 0; m < MTN; ++m) acc[m] = zero4;
#pragma unroll
        for (int kt = 0; kt < 5; ++kt) {
#pragma unroll
            for (int m = 0; m < MTN; ++m) {
                bf16x8 b = *(const bf16x8*)(s_inp + ((mbase + m) * 5 + kt) * 512 + lane * 8);
                acc[m] = MFMA(aw[kt], b, acc[m]);
            }
        }
#pragma unroll
        for (int m = 0; m < MTN; ++m) {
            bf16x4 hv;
#pragma unroll
            for (int rg = 0; rg < 4; ++rg) {
                float z = acc[m][rg] + bias_r[n][rg];
                hv[rg] = (__bf16)((z > 0.f) ? z : 0.f);
            }
            *(bf16x4*)(s_h + (m * 8 + (ht >> 1)) * 512 +
                       ((((ht & 1) * 2 + (q >> 1)) << 4) | c) * 8 + ((q & 1) << 2)) = hv;
        }
    }
}

// stage3 SWAPPED: D'[ncol][row] = MFMA(A=W2-frag, B=h-frag); 8 waves x 2 nt.
template <int MTN, bool DW>
__device__ __forceinline__ void stage3s(int mbase, const __bf16* Wf, const void* Wn,
                                        bool fW, const void* Bb, const void* Rh,
                                        const __bf16* s_h, float* s_qp, int wave, int lane) {
    int q = lane >> 4, c = lane & 15;
    f32x4 zero4 = {0.f, 0.f, 0.f, 0.f};
    float bias_r[2][4], rho_r[2][4];
#pragma unroll
    for (int n = 0; n < 2; ++n)
#pragma unroll
        for (int rg = 0; rg < 4; ++rg) {
            int ncol = (wave * 2 + n) * 16 + q * 4 + rg;
            bias_r[n][rg] = ldf(Bb, ncol, fW);
            rho_r[n][rg] = ldf(Rh, ncol, fW);
        }
    float rowsum[MTN];
#pragma unroll
    for (int m = 0; m < MTN; ++m) rowsum[m] = 0.f;
#pragma unroll
    for (int n = 0; n < 2; ++n) {
        int nt = wave * 2 + n;
        bf16x8 aw[8];
#pragma unroll
        for (int kt = 0; kt < 8; ++kt) {
            if constexpr (DW) aw[kt] = gatherB(Wn, fW, 0, 256, 256, kt * 32, nt * 16 + c, q);
            else aw[kt] = *(const bf16x8*)(Wf + (nt * 8 + kt) * 512 + lane * 8);
        }
        f32x4 acc[MTN];
#pragma unroll
        for (int m = 0; m < MTN; ++m) acc[m] = zero4;
#pragma unroll
        for (int kt = 0; kt < 8; ++kt) {
#pragma unroll
            for (int m = 0; m < MTN; ++m) {
                bf16x8 b = *(const bf16x8*)(s_h + (m * 8 + kt) * 512 + lane * 8);
                acc[m] = MFMA(aw[kt], b, acc[m]);
            }
        }
#pragma unroll
        for (int m = 0; m < MTN; ++m)
#pragma unroll
            for (int rg = 0; rg < 4; ++rg) {
                float z = acc[m][rg] + bias_r[n][rg];
                z = (z > 0.f) ? z : 0.f;
                rowsum[m] += z * rho_r[n][rg];
            }
    }
#pragma unroll
    for (int m = 0; m < MTN; ++m) {
        float v = rowsum[m];
        v += __shfl_xor(v, 16);
        v += __shfl_xor(v, 32);
        if (q == 0) {
            int r0 = (mbase + m) * 16 + c;  // rinp = b*5+o
            atomicAdd(&s_qp[r0 / 5], v);
        }
    }
}

template <bool DW>
__global__ __launch_bounds__(512, 4) void gn_main(
    const void* __restrict__ obs, const void* __restrict__ act,
    const void* __restrict__ ag, const void* __restrict__ g,
    const void* __restrict__ mp_b, const void* __restrict__ b1,
    const void* __restrict__ b2, const void* __restrict__ b3,
    const void* __restrict__ b4, const void* __restrict__ rw1,
    const void* __restrict__ rb1, const void* __restrict__ rw2,
    const void* __restrict__ rb2, const int* __restrict__ eA,
    const int* __restrict__ eB, const int* __restrict__ pred_ids,
    const int* __restrict__ incoming, const __bf16* __restrict__ wsW,
    const void* __restrict__ mp_w, const void* __restrict__ w1,
    const void* __restrict__ w2, const void* __restrict__ w3,
    const void* __restrict__ w4, float* __restrict__ out, int Btot) {
    __shared__ __align__(16) __bf16 s_union[14208];
    __shared__ __align__(16) __bf16 s_inp[12800];
    __shared__ int s_esrc[20], s_pid0[20], s_pid1[20];

    int tid = threadIdx.x, lane = tid & 63, wave = tid >> 6;
    __bf16* rb = s_union + 12288;
    float* s_q = (float*)(s_union + 12288);  // aliases rowbuf head (dead by stage3)
    int b0 = blockIdx.x * 16;

    // ---- dtype flags (per-wave ballot scan; uniform per wave) ----
    bool fI, fW;
    {
        const unsigned short* uo = (const unsigned short*)obs;
        const unsigned short* uw = (const unsigned short*)w2;
        int d0 = 0, d1 = 0;
        for (int i = lane; i < 8192; i += 64) {
            if (((uo[i] >> 7) & 0xFF) == 0xFF) d0 = 1;
            if (((uw[i] >> 7) & 0xFF) == 0xFF) d1 = 1;
        }
        fI = __ballot(d0) != 0;
        fW = __ballot(d1) != 0;
    }

    // ---- int width + src/dst disambiguation ----
    bool i64_i = (incoming[1] == 0);
    bool i64_p = (pred_ids[1] == 0);
    bool i64_e = (eA[9] == 0);
    const int* es = (geti(eA, 4, i64_e) == 1) ? eA : eB;

    if (tid < 20) {
        int e = geti(incoming, tid, i64_i);  // tid = o*4+j; edge p=tid has dst o=tid/4
        s_esrc[tid] = geti(es, e, i64_e);
        s_pid0[tid] = geti(pred_ids, 2 * e, i64_p);
        s_pid1[tid] = geti(pred_ids, 2 * e + 1, i64_p);
    }

    for (int i = tid; i < 16 * 120; i += 512) {
        int lb = i / 120, cidx = i % 120;
        int bg = b0 + lb;
        float v = 0.f;
        if (cidx < 85) v = ldf(obs, bg * 85 + cidx, fI);
        else if (cidx < 89) v = ldf(act, bg * 4 + (cidx - 85), fI);
        else if (cidx < 119) {
            int t = cidx - 89;
            v = ldf(g, bg * 30 + t, fI) - ldf(ag, bg * 30 + t, fI);
        }
        rb[i] = (__bf16)v;
    }
    __syncthreads();

    // inp kt=0 plane (k<32) as b128 blocks
    for (int i = tid; i < 80 * 4; i += 512) {
        int r = i >> 2, oct = i & 3;
        int lb = r / 5, o = r % 5;
        const __bf16* row = rb + lb * 120;
        bf16x8 v;
#pragma unroll
        for (int j = 0; j < 8; ++j) {
            int k = oct * 8 + j;
            __bf16 x = (__bf16)0.f;
            if (k < 4) x = row[85 + k];
            else if (k < 14) x = row[k - 4];
            else if (k < 29) x = row[10 + o * 15 + (k - 14)];
            v[j] = x;
        }
        *(bf16x8*)(s_inp + (r >> 4) * 2560 + ((oct << 4) | (r & 15)) * 8) = v;
    }
    buildA<12, 0>(s_union, rb, s_esrc, s_pid0, s_pid1, tid);
    __syncthreads();
    stage1<12, 0, DW>(wsW + MP_OFF, mp_w, fW, mp_b, s_union, s_inp, wave, lane);
    __syncthreads();
    buildA<8, 12>(s_union, rb, s_esrc, s_pid0, s_pid1, tid);
    __syncthreads();
    if (tid < 32) s_q[tid] = 0.f;  // rowbuf dead from here on
    stage1<8, 12, DW>(wsW + MP_OFF, mp_w, fW, mp_b, s_union, s_inp, wave, lane);
    __syncthreads();

    for (int P = 0; P < 2; ++P) {
        const __bf16* Wa = wsW + (P ? W3_OFF : W1_OFF);
        const __bf16* Wb = wsW + (P ? W4_OFF : W2_OFF);
        const void* Wan = P ? w3 : w1;
        const void* Wbn = P ? w4 : w2;
        const void* ba = P ? b3 : b1;
        const void* bb = P ? b4 : b2;
        const void* rho = P ? rw2 : rw1;
        float* qp = s_q + P * 16;
        stage2s<3, DW>(0, Wa, Wan, fW, ba, s_union, s_inp, wave, lane);
        __syncthreads();
        stage3s<3, DW>(0, Wb, Wbn, fW, bb, rho, s_union, qp, wave, lane);
        __syncthreads();
        stage2s<2, DW>(3, Wa, Wan, fW, ba, s_union, s_inp, wave, lane);
        __syncthreads();
        stage3s<2, DW>(3, Wb, Wbn, fW, bb, rho, s_union, qp, wave, lane);
        __syncthreads();
    }

    if (tid < 16) {
        out[b0 + tid] = s_q[tid] + ldf(rb1, 0, fW);
        out[Btot + b0 + tid] = s_q[16 + tid] + ldf(rb2, 0, fW);
    }
}

extern "C" void kernel_launch(void* const* d_in, const int* in_sizes, int n_in,
                              void* d_out, int out_size, void* d_ws, size_t ws_size,
                              hipStream_t stream) {
    int B = out_size / 2;  // 16384

    const void *obs = nullptr, *act = nullptr, *ag = nullptr, *g = nullptr;
    const void *mp_w = nullptr, *mp_b = nullptr;
    const void *w1 = nullptr, *b1 = nullptr, *w2 = nullptr, *b2 = nullptr;
    const void *w3 = nullptr, *b3 = nullptr, *w4 = nullptr, *b4 = nullptr;
    const void *rw1 = nullptr, *rb1 = nullptr, *rw2 = nullptr, *rb2 = nullptr;
    const int *eA = nullptr, *eB = nullptr, *pred = nullptr, *inc = nullptr;
    int c30 = 0, c256 = 0, c1 = 0, c40k = 0, c65k = 0, c20 = 0;
    for (int i = 0; i < n_in; ++i) {
        int sz = in_sizes[i];
        const void* p = d_in[i];
        if (sz == B * 85) obs = p;
        else if (sz == B * 30) { if (c30++ == 0) ag = p; else g = p; }
        else if (sz == 5888) mp_w = p;
        else if (sz == 128) mp_b = p;
        else if (sz == 40192) { if (c40k++ == 0) w1 = p; else w3 = p; }
        else if (sz == 65536 || sz == B * 4) {
            int c = c65k++;
            if (c == 0) act = p; else if (c == 1) w2 = p; else w4 = p;
        }
        else if (sz == 256) {
            int c = c256++;
            if (c == 0) b1 = p; else if (c == 1) b2 = p; else if (c == 2) b3 = p;
            else if (c == 3) b4 = p; else if (c == 4) rw1 = p; else rw2 = p;
        }
        else if (sz == 1) { if (c1++ == 0) rb1 = p; else rb2 = p; }
        else if (sz == 40) pred = (const int*)p;
        else if (sz == 20) {
            int c = c20++;
            if (c == 0) eA = (const int*)p;
            else if (c == 1) eB = (const int*)p;
            else inc = (const int*)p;
        }
    }
    if (!obs || !act || !ag || !g || !mp_w || !mp_b || !w1 || !b1 || !w2 || !b2 ||
        !w3 || !b3 || !w4 || !b4 || !rw1 || !rb1 || !rw2 || !rb2 || !eA || !eB ||
        !pred || !inc) {
        obs = d_in[0]; act = d_in[1]; ag = d_in[2]; g = d_in[3];
        mp_w = d_in[4]; mp_b = d_in[5]; w1 = d_in[6]; b1 = d_in[7];
        w2 = d_in[8]; b2 = d_in[9]; w3 = d_in[10]; b3 = d_in[11];
        w4 = d_in[12]; b4 = d_in[13]; rw1 = d_in[14]; rb1 = d_in[15];
        rw2 = d_in[16]; rb2 = d_in[17];
        eA = (const int*)d_in[18]; eB = (const int*)d_in[19];
        pred = (const int*)d_in[20]; inc = (const int*)d_in[21];
    }

    float* out = (float*)d_out;
    __bf16* wsW = (__bf16*)d_ws;
    bool use_ws = ws_size >= WS_BYTES;
    int grid = B / 16;

    if (use_ws) {
        swz<<<108, 256, 0, stream>>>(mp_w, w1, w2, w3, w4, wsW);
        gn_main<false><<<grid, 512, 0, stream>>>(
            obs, act, ag, g, mp_b, b1, b2, b3, b4, rw1, rb1, rw2, rb2,
            eA, eB, pred, inc, wsW, mp_w, w1, w2, w3, w4, out, B);
    } else {
        gn_main<true><<<grid, 512, 0, stream>>>(
            obs, act, ag, g, mp_b, b1, b2, b3, b4, rw1, rb1, rw2, rb2,
            eA, eB, pred, inc, wsW, mp_w, w1, w2, w3, w4, out, B);
    }
}